// Round 1
// baseline (379.361 us; speedup 1.0000x reference)
//
#include <hip/hip_runtime.h>
#include <math.h>

#define N_ROWS  32768
#define K_CODES 1024
#define D_DIM   64
#define C_SHIFT 30.0f   // logit shift: keeps expf in fp32 range (row max logit ~ -12, never > ~60)

// ws layout (float indices)
#define WS_E2C   0       // [1024] ||e_k||^2 + C_SHIFT
#define WS_HIST  1024    // [1024] code usage histogram (float counts)
#define WS_ACC_H 2048    // entropy sum (nats) over rows
#define WS_ACC_C 2049    // commitment squared-diff sum
#define WS_NUSED 2050    // count of used codes
#define WS_FLOATS 2051

// out layout (float indices); outputs concatenated in reference return order
#define OUT_Q      0
#define OUT_COMMIT 2097152
#define OUT_ORTHO  2097153
#define OUT_ENT    2097154
#define OUT_PERP   2097155
#define OUT_COV    2097156
#define OUT_IDX    2097157

__global__ __launch_bounds__(256) void vq_prep(const float* __restrict__ emb,
                                               const float* __restrict__ cc,
                                               float* __restrict__ ws) {
    int k = blockIdx.x * blockDim.x + threadIdx.x;
    if (k < K_CODES) {
        const float4* e4 = (const float4*)(emb + (size_t)k * D_DIM);
        float s = 0.f;
#pragma unroll
        for (int j = 0; j < 16; ++j) {
            float4 v = e4[j];
            s += v.x * v.x + v.y * v.y + v.z * v.z + v.w * v.w;
        }
        ws[WS_E2C + k] = s + C_SHIFT;
        if (cc[k] >= 1.0f) atomicAdd(&ws[WS_NUSED], 1.0f);
    }
}

// 512 blocks x 256 threads. Block handles 64 rows (lane = row). Each of the 4
// waves covers 256 codes; partial softmax/argmax state combined via LDS.
__global__ __launch_bounds__(256) void vq_main(const float* __restrict__ inp,
                                               const float* __restrict__ emb,
                                               float* __restrict__ ws,
                                               float* __restrict__ out) {
    __shared__ float Ls[4][64];
    __shared__ float Lu[4][64];
    __shared__ float Lg[4][64];
    __shared__ int   Lk[4][64];

    const int lane = threadIdx.x & 63;
    const int wave = threadIdx.x >> 6;
    const int row  = blockIdx.x * 64 + lane;

    // x row in registers (64 VGPRs)
    float4 X[16];
    const float4* xr = (const float4*)(inp + (size_t)row * D_DIM);
#pragma unroll
    for (int j = 0; j < 16; ++j) X[j] = xr[j];

    // wave-uniform code base -> SGPR so embedding loads can be scalar
    const int kbase = __builtin_amdgcn_readfirstlane(wave << 8);

    float s = 0.f, u = 0.f, gmax = -1e30f;
    int kb = kbase;

    for (int kk = 0; kk < 256; ++kk) {
        const int k = kbase + kk;
        const float4* e4 = (const float4*)(emb + (size_t)k * D_DIM);
        float d0 = 0.f, d1 = 0.f, d2 = 0.f, d3 = 0.f;
#pragma unroll
        for (int j = 0; j < 16; j += 4) {
            float4 ea = e4[j], eb = e4[j + 1], ec = e4[j + 2], ed = e4[j + 3];
            float4 xa = X[j], xb = X[j + 1], xc = X[j + 2], xd = X[j + 3];
            d0 = fmaf(ea.x, xa.x, d0); d0 = fmaf(ea.y, xa.y, d0);
            d0 = fmaf(ea.z, xa.z, d0); d0 = fmaf(ea.w, xa.w, d0);
            d1 = fmaf(eb.x, xb.x, d1); d1 = fmaf(eb.y, xb.y, d1);
            d1 = fmaf(eb.z, xb.z, d1); d1 = fmaf(eb.w, xb.w, d1);
            d2 = fmaf(ec.x, xc.x, d2); d2 = fmaf(ec.y, xc.y, d2);
            d2 = fmaf(ec.z, xc.z, d2); d2 = fmaf(ec.w, xc.w, d2);
            d3 = fmaf(ed.x, xd.x, d3); d3 = fmaf(ed.y, xd.y, d3);
            d3 = fmaf(ed.z, xd.z, d3); d3 = fmaf(ed.w, xd.w, d3);
        }
        float dot = (d0 + d1) + (d2 + d3);
        // shifted logit: g = 2*dot - ||e||^2 - C  (softmax/entropy shift-invariant)
        float g = fmaf(2.0f, dot, -ws[WS_E2C + k]);
        float p = __expf(g);
        s += p;
        u = fmaf(p, g, u);
        if (g > gmax) { gmax = g; kb = k; }   // strict > keeps first index on ties
    }

    Ls[wave][lane] = s;
    Lu[wave][lane] = u;
    Lg[wave][lane] = gmax;
    Lk[wave][lane] = kb;
    __syncthreads();

    if (wave == 0) {
        float S = 0.f, U = 0.f, G = -1e30f;
        int I = 0;
#pragma unroll
        for (int w = 0; w < 4; ++w) {          // ascending k order -> first-min tie break
            S += Ls[w][lane];
            U += Lu[w][lane];
            float gw = Lg[w][lane];
            if (gw > G) { G = gw; I = Lk[w][lane]; }
        }
        float H = logf(S) - U / S;             // -sum p log p (nats), per row

        out[OUT_IDX + row] = (float)I;
        atomicAdd(&ws[WS_HIST + I], 1.0f);

        // quantized output = x + (q - x), commitment = sum (q - x)^2
        const float4* q4 = (const float4*)(emb + (size_t)I * D_DIM);
        float4* oq = (float4*)out + (size_t)row * 16;
        float cs = 0.f;
#pragma unroll
        for (int j = 0; j < 16; ++j) {
            float4 q = q4[j], x = X[j];
            float dx = q.x - x.x, dy = q.y - x.y, dz = q.z - x.z, dw = q.w - x.w;
            cs += dx * dx + dy * dy + dz * dz + dw * dw;
            float4 o;
            o.x = x.x + dx; o.y = x.y + dy; o.z = x.z + dz; o.w = x.w + dw;
            oq[j] = o;
        }
#pragma unroll
        for (int off = 32; off; off >>= 1) {
            H  += __shfl_down(H, off);
            cs += __shfl_down(cs, off);
        }
        if (lane == 0) {
            atomicAdd(&ws[WS_ACC_H], H);
            atomicAdd(&ws[WS_ACC_C], cs);
        }
    }
}

// ortho loss: sum(cos^2) over used codes == ||N^T N||_F^2 with N = masked normed
// embedding; G = N^T N is 64x64. One block, 256 threads; thread owns G[a][b0..b0+15].
__global__ __launch_bounds__(256) void vq_ortho(const float* __restrict__ emb,
                                                const float* __restrict__ cc,
                                                const float* __restrict__ ws,
                                                float* __restrict__ out) {
    __shared__ float rows[16][64];
    __shared__ float rnorm[16];
    __shared__ float red[4];

    const int t  = threadIdx.x;
    const int a  = t >> 2;
    const int b0 = (t & 3) << 4;
    const int r  = t >> 4;          // staging row 0..15
    const int c4 = (t & 15) << 2;   // staging col (float4)

    float acc[16];
#pragma unroll
    for (int i = 0; i < 16; ++i) acc[i] = 0.f;

    for (int kt = 0; kt < K_CODES; kt += 16) {
        float4 v = *(const float4*)(emb + (size_t)(kt + r) * D_DIM + c4);
        *(float4*)(&rows[r][c4]) = v;
        float ss = v.x * v.x + v.y * v.y + v.z * v.z + v.w * v.w;
        ss += __shfl_down(ss, 8, 16);
        ss += __shfl_down(ss, 4, 16);
        ss += __shfl_down(ss, 2, 16);
        ss += __shfl_down(ss, 1, 16);
        if ((t & 15) == 0) {
            float nrm = fmaxf(sqrtf(ss), 1e-12f);
            float m = (cc[kt + r] >= 1.0f) ? 1.0f : 0.0f;
            rnorm[r] = m / nrm;
        }
        __syncthreads();
#pragma unroll 4
        for (int kk = 0; kk < 16; ++kk) {
            float sc = rnorm[kk];
            float na = rows[kk][a] * sc * sc;   // fold both scales into A side
            const float* rb = &rows[kk][b0];
#pragma unroll
            for (int i = 0; i < 16; ++i) acc[i] = fmaf(na, rb[i], acc[i]);
        }
        __syncthreads();
    }

    float ssq = 0.f;
#pragma unroll
    for (int i = 0; i < 16; ++i) ssq = fmaf(acc[i], acc[i], ssq);
#pragma unroll
    for (int off = 32; off; off >>= 1) ssq += __shfl_down(ssq, off);
    if ((t & 63) == 0) red[t >> 6] = ssq;
    __syncthreads();
    if (t == 0) {
        float tot = red[0] + red[1] + red[2] + red[3];
        float nu = ws[WS_NUSED];
        out[OUT_ORTHO] = tot / (nu * nu) - 1.0f / nu;
    }
}

__global__ __launch_bounds__(256) void vq_finalize(const float* __restrict__ ws,
                                                   float* __restrict__ out) {
    __shared__ float red[4];
    const int t = threadIdx.x;
    float local = 0.f;
    for (int k = t; k < K_CODES; k += 256) {
        float p = ws[WS_HIST + k] * (1.0f / (float)N_ROWS);
        local += p * logf(p + 1e-10f);
    }
#pragma unroll
    for (int off = 32; off; off >>= 1) local += __shfl_down(local, off);
    if ((t & 63) == 0) red[t >> 6] = local;
    __syncthreads();
    if (t == 0) {
        float sum = red[0] + red[1] + red[2] + red[3];
        out[OUT_PERP]   = expf(-sum);
        out[OUT_ENT]    = ws[WS_ACC_H] * (1.0f / (float)N_ROWS) * 0.1f; // / log2(1024)
        out[OUT_COMMIT] = ws[WS_ACC_C] * (1.0f / ((float)N_ROWS * (float)D_DIM));
        out[OUT_COV]    = ws[WS_NUSED] * (1.0f / (float)K_CODES);
    }
}

extern "C" void kernel_launch(void* const* d_in, const int* in_sizes, int n_in,
                              void* d_out, int out_size, void* d_ws, size_t ws_size,
                              hipStream_t stream) {
    const float* inp = (const float*)d_in[0];   // [16,2048,64]
    const float* emb = (const float*)d_in[1];   // [1024,64]
    const float* cc  = (const float*)d_in[2];   // [1024]
    float* out = (float*)d_out;
    float* ws  = (float*)d_ws;

    hipMemsetAsync(d_ws, 0, WS_FLOATS * sizeof(float), stream);
    vq_prep<<<4, 256, 0, stream>>>(emb, cc, ws);
    vq_main<<<N_ROWS / 64, 256, 0, stream>>>(inp, emb, ws, out);
    vq_ortho<<<1, 256, 0, stream>>>(emb, cc, ws, out);
    vq_finalize<<<1, 256, 0, stream>>>(ws, out);
}

// Round 2
// 188.514 us; speedup vs baseline: 2.0124x; 2.0124x over previous
//
#include <hip/hip_runtime.h>
#include <math.h>

#define N_ROWS  32768
#define K_CODES 1024
#define D_DIM   64
#define NSPLIT  4            // K-splits across blocks
#define C_SHIFT 30.0f        // logit shift keeps expf in fp32 range

// ---- ws float-index layout ----
#define WS_HIST   0                       // [1024] histogram (memset)
#define WS_ACC_H  1024                    // entropy sum (nats)
#define WS_ACC_C  1025                    // commitment sq-diff sum
#define WS_NUSED  1026                    // used-code count
#define WS_G      2048                    // [4096] 64x64 gram partial-summed (memset)
#define WS_E2C    6144                    // [1024] ||e||^2 + C_SHIFT
#define WS_PART   8192                    // 4 arrays of [NSPLIT*N_ROWS]
#define PART_STRIDE (NSPLIT * N_ROWS)     // 131072
#define WS_PART_S (WS_PART)
#define WS_PART_U (WS_PART + PART_STRIDE)
#define WS_PART_G (WS_PART + 2 * PART_STRIDE)
#define WS_PART_K (WS_PART + 3 * PART_STRIDE)
#define MEMSET_BYTES (6144 * 4)           // hist + accs + gram

// ---- out float-index layout (reference return order, concatenated) ----
#define OUT_Q      0
#define OUT_COMMIT 2097152
#define OUT_ORTHO  2097153
#define OUT_ENT    2097154
#define OUT_PERP   2097155
#define OUT_COV    2097156
#define OUT_IDX    2097157

__global__ __launch_bounds__(256) void vq_prep(const float* __restrict__ emb,
                                               const float* __restrict__ cc,
                                               float* __restrict__ ws) {
    int k = blockIdx.x * blockDim.x + threadIdx.x;
    if (k < K_CODES) {
        const float4* e4 = (const float4*)(emb + (size_t)k * D_DIM);
        float s = 0.f;
#pragma unroll
        for (int j = 0; j < 16; ++j) {
            float4 v = e4[j];
            s += v.x * v.x + v.y * v.y + v.z * v.z + v.w * v.w;
        }
        ws[WS_E2C + k] = s + C_SHIFT;
        if (cc[k] >= 1.0f) atomicAdd(&ws[WS_NUSED], 1.0f);
    }
}

// 2048 blocks x 256 threads. Block = (row-group, k-split): 64 rows (lane=row),
// 256 codes (64 per wave). Writes per-(row,split) softmax/argmax partials.
__global__ __launch_bounds__(256) void vq_main(const float* __restrict__ inp,
                                               const float* __restrict__ emb,
                                               float* __restrict__ ws) {
    __shared__ float Ls[4][64];
    __shared__ float Lu[4][64];
    __shared__ float Lg[4][64];
    __shared__ int   Lk[4][64];

    const int lane = threadIdx.x & 63;
    const int wave = threadIdx.x >> 6;
    const int rg   = blockIdx.x >> 2;      // row group 0..511
    const int sp   = blockIdx.x & 3;       // k split  0..3
    const int row  = rg * 64 + lane;

    float4 X[16];
    const float4* xr = (const float4*)(inp + (size_t)row * D_DIM);
#pragma unroll
    for (int j = 0; j < 16; ++j) X[j] = xr[j];

    // wave-uniform code base -> SGPR so embedding loads stay scalar
    const int kbase = __builtin_amdgcn_readfirstlane(sp * 256 + wave * 64);

    float s = 0.f, u = 0.f, gmax = -1e30f;
    int kb = kbase;

    for (int kk = 0; kk < 64; ++kk) {
        const int k = kbase + kk;
        const float4* e4 = (const float4*)(emb + (size_t)k * D_DIM);
        float d0 = 0.f, d1 = 0.f, d2 = 0.f, d3 = 0.f;
#pragma unroll
        for (int j = 0; j < 16; j += 4) {
            float4 ea = e4[j], eb = e4[j + 1], ec = e4[j + 2], ed = e4[j + 3];
            float4 xa = X[j], xb = X[j + 1], xc = X[j + 2], xd = X[j + 3];
            d0 = fmaf(ea.x, xa.x, d0); d0 = fmaf(ea.y, xa.y, d0);
            d0 = fmaf(ea.z, xa.z, d0); d0 = fmaf(ea.w, xa.w, d0);
            d1 = fmaf(eb.x, xb.x, d1); d1 = fmaf(eb.y, xb.y, d1);
            d1 = fmaf(eb.z, xb.z, d1); d1 = fmaf(eb.w, xb.w, d1);
            d2 = fmaf(ec.x, xc.x, d2); d2 = fmaf(ec.y, xc.y, d2);
            d2 = fmaf(ec.z, xc.z, d2); d2 = fmaf(ec.w, xc.w, d2);
            d3 = fmaf(ed.x, xd.x, d3); d3 = fmaf(ed.y, xd.y, d3);
            d3 = fmaf(ed.z, xd.z, d3); d3 = fmaf(ed.w, xd.w, d3);
        }
        float dot = (d0 + d1) + (d2 + d3);
        float g = fmaf(2.0f, dot, -ws[WS_E2C + k]);   // shifted logit
        float p = __expf(g);
        s += p;
        u = fmaf(p, g, u);
        if (g > gmax) { gmax = g; kb = k; }           // strict > = first-index ties
    }

    Ls[wave][lane] = s;
    Lu[wave][lane] = u;
    Lg[wave][lane] = gmax;
    Lk[wave][lane] = kb;
    __syncthreads();

    if (wave == 0) {
        float S = 0.f, U = 0.f, G = -1e30f;
        int I = 0;
#pragma unroll
        for (int w = 0; w < 4; ++w) {                 // ascending k order
            S += Ls[w][lane];
            U += Lu[w][lane];
            float gw = Lg[w][lane];
            if (gw > G) { G = gw; I = Lk[w][lane]; }
        }
        const int pi = sp * N_ROWS + row;
        ws[WS_PART_S + pi] = S;
        ws[WS_PART_U + pi] = U;
        ws[WS_PART_G + pi] = G;
        ws[WS_PART_K + pi] = (float)I;
    }
}

// 128 blocks x 256 threads; thread = row. Merge NSPLIT partials, epilogue.
__global__ __launch_bounds__(256) void vq_combine(const float* __restrict__ inp,
                                                  const float* __restrict__ emb,
                                                  float* __restrict__ ws,
                                                  float* __restrict__ out) {
    __shared__ float redH[4], redC[4];
    const int t   = threadIdx.x;
    const int row = blockIdx.x * 256 + t;

    float S = 0.f, U = 0.f, G = -1e30f;
    int I = 0;
#pragma unroll
    for (int sp = 0; sp < NSPLIT; ++sp) {             // ascending split order
        const int pi = sp * N_ROWS + row;
        S += ws[WS_PART_S + pi];
        U += ws[WS_PART_U + pi];
        float g = ws[WS_PART_G + pi];
        if (g > G) { G = g; I = (int)ws[WS_PART_K + pi]; }
    }
    float H = logf(S) - U / S;                        // per-row entropy (nats)

    out[OUT_IDX + row] = (float)I;
    atomicAdd(&ws[WS_HIST + I], 1.0f);

    const float4* xr = (const float4*)(inp + (size_t)row * D_DIM);
    const float4* q4 = (const float4*)(emb + (size_t)I * D_DIM);
    float4* oq = (float4*)out + (size_t)row * 16;
    float cs = 0.f;
#pragma unroll
    for (int j = 0; j < 16; ++j) {
        float4 q = q4[j], x = xr[j];
        float dx = q.x - x.x, dy = q.y - x.y, dz = q.z - x.z, dw = q.w - x.w;
        cs += dx * dx + dy * dy + dz * dz + dw * dw;
        float4 o;
        o.x = x.x + dx; o.y = x.y + dy; o.z = x.z + dz; o.w = x.w + dw;
        oq[j] = o;
    }
#pragma unroll
    for (int off = 32; off; off >>= 1) {
        H  += __shfl_down(H, off);
        cs += __shfl_down(cs, off);
    }
    if ((t & 63) == 0) { redH[t >> 6] = H; redC[t >> 6] = cs; }
    __syncthreads();
    if (t == 0) {
        atomicAdd(&ws[WS_ACC_H], redH[0] + redH[1] + redH[2] + redH[3]);
        atomicAdd(&ws[WS_ACC_C], redC[0] + redC[1] + redC[2] + redC[3]);
    }
}

// 16 blocks x 256 threads; block b owns codes [64b, 64b+64). Partial 64x64
// Gram of masked-normalized rows, atomicAdd into ws[WS_G].
__global__ __launch_bounds__(256) void vq_ortho_part(const float* __restrict__ emb,
                                                     const float* __restrict__ cc,
                                                     float* __restrict__ ws) {
    __shared__ float srows[64][64];
    __shared__ float rn2[64];

    const int t  = threadIdx.x;
    const int k0 = blockIdx.x * 64;
    const int rb = t >> 4;            // 0..15
    const int c4 = (t & 15) << 2;     // float4 col

#pragma unroll
    for (int i = 0; i < 4; ++i) {
        const int r = i * 16 + rb;
        float4 v = *(const float4*)(emb + (size_t)(k0 + r) * D_DIM + c4);
        *(float4*)(&srows[r][c4]) = v;
        float ss = v.x * v.x + v.y * v.y + v.z * v.z + v.w * v.w;
        ss += __shfl_down(ss, 8, 16);
        ss += __shfl_down(ss, 4, 16);
        ss += __shfl_down(ss, 2, 16);
        ss += __shfl_down(ss, 1, 16);
        if ((t & 15) == 0) {
            float nrm = fmaxf(sqrtf(ss), 1e-12f);
            float m = (cc[k0 + r] >= 1.0f) ? 1.0f : 0.0f;
            rn2[r] = m / (nrm * nrm);     // rnorm^2, folded into A side
        }
    }
    __syncthreads();

    const int a  = t >> 2;
    const int b0 = (t & 3) << 4;
    float acc[16];
#pragma unroll
    for (int i = 0; i < 16; ++i) acc[i] = 0.f;

#pragma unroll 4
    for (int k = 0; k < 64; ++k) {
        float na = srows[k][a] * rn2[k];
        const float* rbp = &srows[k][b0];
#pragma unroll
        for (int i = 0; i < 16; ++i) acc[i] = fmaf(na, rbp[i], acc[i]);
    }
#pragma unroll
    for (int i = 0; i < 16; ++i)
        atomicAdd(&ws[WS_G + a * 64 + b0 + i], acc[i]);
}

__global__ __launch_bounds__(256) void vq_finalize(const float* __restrict__ ws,
                                                   float* __restrict__ out) {
    __shared__ float redP[4], redG[4];
    const int t = threadIdx.x;
    float hp = 0.f, gg = 0.f;
    for (int k = t; k < K_CODES; k += 256) {
        float p = ws[WS_HIST + k] * (1.0f / (float)N_ROWS);
        hp += p * logf(p + 1e-10f);
    }
    for (int i = t; i < 4096; i += 256) {
        float g = ws[WS_G + i];
        gg = fmaf(g, g, gg);
    }
#pragma unroll
    for (int off = 32; off; off >>= 1) {
        hp += __shfl_down(hp, off);
        gg += __shfl_down(gg, off);
    }
    if ((t & 63) == 0) { redP[t >> 6] = hp; redG[t >> 6] = gg; }
    __syncthreads();
    if (t == 0) {
        float hsum = redP[0] + redP[1] + redP[2] + redP[3];
        float gsum = redG[0] + redG[1] + redG[2] + redG[3];
        float nu = ws[WS_NUSED];
        out[OUT_PERP]   = expf(-hsum);
        out[OUT_ENT]    = ws[WS_ACC_H] * (1.0f / (float)N_ROWS) * 0.1f; // /log2(1024)
        out[OUT_COMMIT] = ws[WS_ACC_C] * (1.0f / ((float)N_ROWS * (float)D_DIM));
        out[OUT_ORTHO]  = gsum / (nu * nu) - 1.0f / nu;
        out[OUT_COV]    = nu * (1.0f / (float)K_CODES);
    }
}

extern "C" void kernel_launch(void* const* d_in, const int* in_sizes, int n_in,
                              void* d_out, int out_size, void* d_ws, size_t ws_size,
                              hipStream_t stream) {
    const float* inp = (const float*)d_in[0];   // [16,2048,64]
    const float* emb = (const float*)d_in[1];   // [1024,64]
    const float* cc  = (const float*)d_in[2];   // [1024]
    float* out = (float*)d_out;
    float* ws  = (float*)d_ws;

    hipMemsetAsync(d_ws, 0, MEMSET_BYTES, stream);
    vq_prep<<<4, 256, 0, stream>>>(emb, cc, ws);
    vq_main<<<(N_ROWS / 64) * NSPLIT, 256, 0, stream>>>(inp, emb, ws);
    vq_combine<<<N_ROWS / 256, 256, 0, stream>>>(inp, emb, ws, out);
    vq_ortho_part<<<16, 256, 0, stream>>>(emb, cc, ws);
    vq_finalize<<<1, 256, 0, stream>>>(ws, out);
}